// Round 4
// baseline (603.423 us; speedup 1.0000x reference)
//
#include <hip/hip_runtime.h>
#include <hip/hip_bf16.h>
#include <cstdint>

#define NCLOUDS 16
#define N_PER   2048
#define KNN_K   16
#define CAP     48

typedef unsigned long long u64;

// ---------------------------------------------------------------------------
// KNN v4: grid = 512 blocks (16 clouds x 32 qblocks) = exactly 2 blocks/CU.
// Block = 512 thr = 8 waves; wave handles 8 queries sequentially; the wave's
// 64 lanes each hold 32 candidates IN REGISTERS (one-time global load,
// interleaved mapping c = ((qblk+jj)&31)*64 + lane so slot 0 = the block's
// own queries -> Q via static-index shfl). Pass 1: per-lane min d2 (fma).
// Threshold: f32 bitonic over 64 lane-minima, T = 16th smallest * (1+1e-5)
// (>= true 16th-NN d2: 16 actual values lie at or below it; inflation covers
// fma-vs-reference rounding, which has no cancellation). Pass 2: exact
// reference-association d2, collect (d2,idx) u64 for d2<=T into LDS buf.
// Select: 64-lane u64 bitonic -> lanes 0..15 write exact (d2 asc, idx asc).
// ---------------------------------------------------------------------------
__global__ __launch_bounds__(512, 4) void knn_kernel(const float* __restrict__ pos,
                                                     int* __restrict__ knn_out)
{
    __shared__ u64 buf[64][CAP];
    __shared__ int cnt[64];

    const int cloud = blockIdx.x >> 5;
    const int qblk  = blockIdx.x & 31;
    const int tid   = threadIdx.x;
    const int wave  = tid >> 6;
    const int lane  = tid & 63;

    if (tid < 64) cnt[tid] = 0;
    __syncthreads();

    const int b0 = cloud * N_PER;

    // candidate registers: slot jj holds point ((qblk+jj)&31)*64 + lane
    float cx[32], cy[32], cz[32];
#pragma unroll
    for (int jj = 0; jj < 32; ++jj) {
        const int c = (((qblk + jj) & 31) << 6) + lane;
        const float* p = pos + (size_t)(b0 + c) * 3;
        cx[jj] = p[0]; cy[jj] = p[1]; cz[jj] = p[2];
    }

#pragma unroll 1
    for (int qi = 0; qi < 8; ++qi) {
        const int qloc = wave * 8 + qi;        // query id within block
        const float Qx = __shfl(cx[0], qloc);
        const float Qy = __shfl(cy[0], qloc);
        const float Qz = __shfl(cz[0], qloc);

        // ---- pass 1: per-lane min d2 (fast fma form; threshold use only) ----
        float mn = __builtin_inff();
#pragma unroll
        for (int jj = 0; jj < 32; ++jj) {
            const float dx = Qx - cx[jj];
            const float dy = Qy - cy[jj];
            const float dz = Qz - cz[jj];
            mn = fminf(mn, fmaf(dx, dx, fmaf(dy, dy, dz * dz)));
        }

        // ---- bitonic ascending sort of 64 lane-minima -> 16th smallest ----
        float v = mn;
#pragma unroll
        for (int k = 2; k <= 64; k <<= 1) {
#pragma unroll
            for (int j = k >> 1; j >= 1; j >>= 1) {
                const float o = __shfl_xor(v, j);
                const bool keepmin = (((lane & j) == 0) == ((lane & k) == 0));
                v = keepmin ? fminf(v, o) : fmaxf(v, o);
            }
        }
        const float T = __shfl(v, KNN_K - 1) * (1.0f + 1e-5f);

        // ---- pass 2: exact d2 (reference association), collect <= T ----
#pragma unroll
        for (int jj = 0; jj < 32; ++jj) {
            const float dx = __fsub_rn(Qx, cx[jj]);
            const float dy = __fsub_rn(Qy, cy[jj]);
            const float dz = __fsub_rn(Qz, cz[jj]);
            const float d2 = __fadd_rn(__fadd_rn(__fmul_rn(dx, dx), __fmul_rn(dy, dy)),
                                       __fmul_rn(dz, dz));
            if (d2 <= T) {
                const int slot = atomicAdd(&cnt[qloc], 1);
                if (slot < CAP) {
                    const int c = (((qblk + jj) & 31) << 6) + lane;
                    buf[qloc][slot] = ((u64)__float_as_uint(d2) << 32) | (unsigned)c;
                }
            }
        }
        asm volatile("s_waitcnt lgkmcnt(0)" ::: "memory");

        // ---- select: 64-lane u64 bitonic, lanes 0..15 emit top-16 ----
        const int n = min(cnt[qloc], CAP);
        u64 key = (lane < n) ? buf[qloc][lane] : ~0ULL;
#pragma unroll
        for (int k = 2; k <= 64; k <<= 1) {
#pragma unroll
            for (int j = k >> 1; j >= 1; j >>= 1) {
                const u64 o = __shfl_xor(key, j);
                const bool keepmin = (((lane & j) == 0) == ((lane & k) == 0));
                const u64 lo = key < o ? key : o;
                const u64 hi = key < o ? o : key;
                key = keepmin ? lo : hi;
            }
        }
        if (lane < KNN_K)
            knn_out[((size_t)b0 + qblk * 64 + qloc) * KNN_K + lane] =
                b0 + (int)(unsigned)(key & 0xffffffffu);
    }
}

// ---------------------------------------------------------------------------
// Edge-MLP layer: lane = one edge (point p, neighbor slot k). hidden[32] and
// per-edge out in registers; weights are wave-uniform (scalar loads).
// Max over the 16 edge-lanes of each point via shfl_xor butterfly.
// ---------------------------------------------------------------------------
template <int CH>
__global__ __launch_bounds__(256) void layer_kernel(
    const float* __restrict__ pos,
    const float* __restrict__ hin,
    const int*   __restrict__ knn,
    const float* __restrict__ Wa, const float* __restrict__ ba,
    const float* __restrict__ Wb, const float* __restrict__ bb,
    float* __restrict__ hout)
{
    const int g = blockIdx.x * 256 + threadIdx.x;
    const int p = g >> 4;
    const int k = g & 15;
    const int j = knn[(size_t)p * KNN_K + k];

    float xh[CH];
    if constexpr (CH == 32) {
        const float4* hin4 = (const float4*)hin;   // rows are 128B-aligned
#pragma unroll
        for (int c4 = 0; c4 < 8; ++c4) {
            float4 t = hin4[(size_t)j * 8 + c4];
            xh[4 * c4 + 0] = t.x; xh[4 * c4 + 1] = t.y;
            xh[4 * c4 + 2] = t.z; xh[4 * c4 + 3] = t.w;
        }
    } else {
#pragma unroll
        for (int c = 0; c < CH; ++c) xh[c] = hin[(size_t)j * CH + c];
    }
    float sp[3];
#pragma unroll
    for (int d = 0; d < 3; ++d) sp[d] = pos[(size_t)j * 3 + d] - pos[(size_t)p * 3 + d];

    float hid[32];
#pragma unroll
    for (int c = 0; c < 32; ++c) {
        float s = ba[c];
#pragma unroll
        for (int d = 0; d < CH; ++d) s = fmaf(xh[d], Wa[d * 32 + c], s);
#pragma unroll
        for (int d = 0; d < 3; ++d)  s = fmaf(sp[d], Wa[(CH + d) * 32 + c], s);
        hid[c] = fmaxf(s, 0.0f);
    }

    float o0 = 0.0f, o1 = 0.0f;
#pragma unroll
    for (int c2 = 0; c2 < 32; ++c2) {
        float s = bb[c2];
#pragma unroll
        for (int c = 0; c < 32; ++c) s = fmaf(hid[c], Wb[c * 32 + c2], s);
        s = fmaxf(s, __shfl_xor(s, 1));
        s = fmaxf(s, __shfl_xor(s, 2));
        s = fmaxf(s, __shfl_xor(s, 4));
        s = fmaxf(s, __shfl_xor(s, 8));
        if ((c2 & 15) == k) { if (c2 < 16) o0 = s; else o1 = s; }
    }
    hout[(size_t)p * 32 + k]      = fmaxf(o0, 0.0f);
    hout[(size_t)p * 32 + 16 + k] = fmaxf(o1, 0.0f);
}

// ---------------------------------------------------------------------------
// Global max pool over each cloud + linear classifier. 1 block per cloud.
// ---------------------------------------------------------------------------
__global__ __launch_bounds__(256) void pool_kernel(
    const float* __restrict__ h2, const float* __restrict__ Wc,
    const float* __restrict__ bc, float* __restrict__ out)
{
    __shared__ float red[8][32];
    __shared__ float sg[32];
    const int cloud = blockIdx.x;
    const int t = threadIdx.x;
    const int c = t & 31, row = t >> 5;
    float m = 0.0f;  // h2 >= 0 after relu
    for (int p = row; p < N_PER; p += 8)
        m = fmaxf(m, h2[((size_t)cloud * N_PER + p) * 32 + c]);
    red[row][c] = m;
    __syncthreads();
    if (t < 32) {
        float gv = red[0][t];
#pragma unroll
        for (int r = 1; r < 8; ++r) gv = fmaxf(gv, red[r][t]);
        sg[t] = gv;
    }
    __syncthreads();
    if (t < 10) {
        float s = bc[t];
#pragma unroll
        for (int c0 = 0; c0 < 32; ++c0) s = fmaf(sg[c0], Wc[c0 * 10 + t], s);
        out[cloud * 10 + t] = s;
    }
}

extern "C" void kernel_launch(void* const* d_in, const int* in_sizes, int n_in,
                              void* d_out, int out_size, void* d_ws, size_t ws_size,
                              hipStream_t stream)
{
    const float* pos = (const float*)d_in[0];
    const float* W1a = (const float*)d_in[2];
    const float* b1a = (const float*)d_in[3];
    const float* W1b = (const float*)d_in[4];
    const float* b1b = (const float*)d_in[5];
    const float* W2a = (const float*)d_in[6];
    const float* b2a = (const float*)d_in[7];
    const float* W2b = (const float*)d_in[8];
    const float* b2b = (const float*)d_in[9];
    const float* Wc  = (const float*)d_in[10];
    const float* bc  = (const float*)d_in[11];

    int*   knn = (int*)d_ws;                                  // 2 MB
    float* h1  = (float*)((char*)d_ws + (size_t)(2 << 20));   // 4 MB
    float* h2  = (float*)((char*)d_ws + (size_t)(6 << 20));   // 4 MB
    float* out = (float*)d_out;

    knn_kernel<<<dim3(NCLOUDS * 32), dim3(512), 0, stream>>>(pos, knn);
    layer_kernel<3><<<dim3((NCLOUDS * N_PER * KNN_K) / 256), dim3(256), 0, stream>>>(
        pos, pos, knn, W1a, b1a, W1b, b1b, h1);
    layer_kernel<32><<<dim3((NCLOUDS * N_PER * KNN_K) / 256), dim3(256), 0, stream>>>(
        pos, h1, knn, W2a, b2a, W2b, b2b, h2);
    pool_kernel<<<dim3(NCLOUDS), dim3(256), 0, stream>>>(h2, Wc, bc, out);
}

// Round 5
// 192.266 us; speedup vs baseline: 3.1385x; 3.1385x over previous
//
#include <hip/hip_runtime.h>
#include <hip/hip_bf16.h>
#include <cstdint>

#define NCLOUDS 16
#define N_PER   2048
#define KNN_K   16
#define CAP     48

typedef unsigned long long u64;

// ---------------------------------------------------------------------------
// KNN v5 (= v4 + launch_bounds(512,2) so candidate arrays stay in VGPRs;
// v4's (512,4) capped VGPR at 128 -> alloca not promoted -> 917MB scratch).
// grid = 512 blocks (16 clouds x 32 qblocks). Block = 512 thr = 8 waves;
// wave handles 8 queries sequentially; the wave's 64 lanes hold 32 candidates
// each IN REGISTERS (96 VGPRs), interleaved mapping c = ((qblk+jj)&31)*64+lane
// so slot 0 = the block's own 64 queries -> Q via static-index shfl.
// Pass 1: per-lane min d2 (fma form). Threshold: f32 bitonic over the 64
// lane-minima; T = 16th smallest * (1+1e-5) is an upper bound on the true
// 16th-NN d2 (16 actual values lie at/below it; inflation covers fma-vs-
// reference rounding, no cancellation in a sum of squares). Pass 2: exact
// reference-association d2, collect (d2,idx) u64 into LDS buf for d2<=T.
// Select: 64-lane u64 bitonic -> lanes 0..15 emit exact (d2 asc, idx asc),
// matching jax.lax.top_k tie order.
// ---------------------------------------------------------------------------
__global__ __launch_bounds__(512, 2) void knn_kernel(const float* __restrict__ pos,
                                                     int* __restrict__ knn_out)
{
    __shared__ u64 buf[64][CAP];
    __shared__ int cnt[64];

    const int cloud = blockIdx.x >> 5;
    const int qblk  = blockIdx.x & 31;
    const int tid   = threadIdx.x;
    const int wave  = tid >> 6;
    const int lane  = tid & 63;

    if (tid < 64) cnt[tid] = 0;
    __syncthreads();

    const int b0 = cloud * N_PER;

    // candidate registers: slot jj holds point ((qblk+jj)&31)*64 + lane
    float cx[32], cy[32], cz[32];
#pragma unroll
    for (int jj = 0; jj < 32; ++jj) {
        const int c = (((qblk + jj) & 31) << 6) + lane;
        const float* p = pos + (size_t)(b0 + c) * 3;
        cx[jj] = p[0]; cy[jj] = p[1]; cz[jj] = p[2];
    }

#pragma unroll 1
    for (int qi = 0; qi < 8; ++qi) {
        const int qloc = wave * 8 + qi;        // query id within block
        const float Qx = __shfl(cx[0], qloc);
        const float Qy = __shfl(cy[0], qloc);
        const float Qz = __shfl(cz[0], qloc);

        // ---- pass 1: per-lane min d2 (fast fma form; threshold use only) ----
        float mn = __builtin_inff();
#pragma unroll
        for (int jj = 0; jj < 32; ++jj) {
            const float dx = Qx - cx[jj];
            const float dy = Qy - cy[jj];
            const float dz = Qz - cz[jj];
            mn = fminf(mn, fmaf(dx, dx, fmaf(dy, dy, dz * dz)));
        }

        // ---- bitonic ascending sort of 64 lane-minima -> 16th smallest ----
        float v = mn;
#pragma unroll
        for (int k = 2; k <= 64; k <<= 1) {
#pragma unroll
            for (int j = k >> 1; j >= 1; j >>= 1) {
                const float o = __shfl_xor(v, j);
                const bool keepmin = (((lane & j) == 0) == ((lane & k) == 0));
                v = keepmin ? fminf(v, o) : fmaxf(v, o);
            }
        }
        const float T = __shfl(v, KNN_K - 1) * (1.0f + 1e-5f);

        // ---- pass 2: exact d2 (reference association), collect <= T ----
#pragma unroll
        for (int jj = 0; jj < 32; ++jj) {
            const float dx = __fsub_rn(Qx, cx[jj]);
            const float dy = __fsub_rn(Qy, cy[jj]);
            const float dz = __fsub_rn(Qz, cz[jj]);
            const float d2 = __fadd_rn(__fadd_rn(__fmul_rn(dx, dx), __fmul_rn(dy, dy)),
                                       __fmul_rn(dz, dz));
            if (d2 <= T) {
                const int slot = atomicAdd(&cnt[qloc], 1);
                if (slot < CAP) {
                    const int c = (((qblk + jj) & 31) << 6) + lane;
                    buf[qloc][slot] = ((u64)__float_as_uint(d2) << 32) | (unsigned)c;
                }
            }
        }
        asm volatile("s_waitcnt lgkmcnt(0)" ::: "memory");

        // ---- select: 64-lane u64 bitonic, lanes 0..15 emit top-16 ----
        const int n = min(cnt[qloc], CAP);
        u64 key = (lane < n) ? buf[qloc][lane] : ~0ULL;
#pragma unroll
        for (int k = 2; k <= 64; k <<= 1) {
#pragma unroll
            for (int j = k >> 1; j >= 1; j >>= 1) {
                const u64 o = __shfl_xor(key, j);
                const bool keepmin = (((lane & j) == 0) == ((lane & k) == 0));
                const u64 lo = key < o ? key : o;
                const u64 hi = key < o ? o : key;
                key = keepmin ? lo : hi;
            }
        }
        if (lane < KNN_K)
            knn_out[((size_t)b0 + qblk * 64 + qloc) * KNN_K + lane] =
                b0 + (int)(unsigned)(key & 0xffffffffu);
    }
}

// ---------------------------------------------------------------------------
// Edge-MLP layer: lane = one edge (point p, neighbor slot k). hidden[32] and
// per-edge out in registers; weights are wave-uniform (scalar loads).
// Max over the 16 edge-lanes of each point via shfl_xor butterfly.
// ---------------------------------------------------------------------------
template <int CH>
__global__ __launch_bounds__(256) void layer_kernel(
    const float* __restrict__ pos,
    const float* __restrict__ hin,
    const int*   __restrict__ knn,
    const float* __restrict__ Wa, const float* __restrict__ ba,
    const float* __restrict__ Wb, const float* __restrict__ bb,
    float* __restrict__ hout)
{
    const int g = blockIdx.x * 256 + threadIdx.x;
    const int p = g >> 4;
    const int k = g & 15;
    const int j = knn[(size_t)p * KNN_K + k];

    float xh[CH];
    if constexpr (CH == 32) {
        const float4* hin4 = (const float4*)hin;   // rows are 128B-aligned
#pragma unroll
        for (int c4 = 0; c4 < 8; ++c4) {
            float4 t = hin4[(size_t)j * 8 + c4];
            xh[4 * c4 + 0] = t.x; xh[4 * c4 + 1] = t.y;
            xh[4 * c4 + 2] = t.z; xh[4 * c4 + 3] = t.w;
        }
    } else {
#pragma unroll
        for (int c = 0; c < CH; ++c) xh[c] = hin[(size_t)j * CH + c];
    }
    float sp[3];
#pragma unroll
    for (int d = 0; d < 3; ++d) sp[d] = pos[(size_t)j * 3 + d] - pos[(size_t)p * 3 + d];

    float hid[32];
#pragma unroll
    for (int c = 0; c < 32; ++c) {
        float s = ba[c];
#pragma unroll
        for (int d = 0; d < CH; ++d) s = fmaf(xh[d], Wa[d * 32 + c], s);
#pragma unroll
        for (int d = 0; d < 3; ++d)  s = fmaf(sp[d], Wa[(CH + d) * 32 + c], s);
        hid[c] = fmaxf(s, 0.0f);
    }

    float o0 = 0.0f, o1 = 0.0f;
#pragma unroll
    for (int c2 = 0; c2 < 32; ++c2) {
        float s = bb[c2];
#pragma unroll
        for (int c = 0; c < 32; ++c) s = fmaf(hid[c], Wb[c * 32 + c2], s);
        s = fmaxf(s, __shfl_xor(s, 1));
        s = fmaxf(s, __shfl_xor(s, 2));
        s = fmaxf(s, __shfl_xor(s, 4));
        s = fmaxf(s, __shfl_xor(s, 8));
        if ((c2 & 15) == k) { if (c2 < 16) o0 = s; else o1 = s; }
    }
    hout[(size_t)p * 32 + k]      = fmaxf(o0, 0.0f);
    hout[(size_t)p * 32 + 16 + k] = fmaxf(o1, 0.0f);
}

// ---------------------------------------------------------------------------
// Global max pool over each cloud + linear classifier. 1 block per cloud.
// ---------------------------------------------------------------------------
__global__ __launch_bounds__(256) void pool_kernel(
    const float* __restrict__ h2, const float* __restrict__ Wc,
    const float* __restrict__ bc, float* __restrict__ out)
{
    __shared__ float red[8][32];
    __shared__ float sg[32];
    const int cloud = blockIdx.x;
    const int t = threadIdx.x;
    const int c = t & 31, row = t >> 5;
    float m = 0.0f;  // h2 >= 0 after relu
    for (int p = row; p < N_PER; p += 8)
        m = fmaxf(m, h2[((size_t)cloud * N_PER + p) * 32 + c]);
    red[row][c] = m;
    __syncthreads();
    if (t < 32) {
        float gv = red[0][t];
#pragma unroll
        for (int r = 1; r < 8; ++r) gv = fmaxf(gv, red[r][t]);
        sg[t] = gv;
    }
    __syncthreads();
    if (t < 10) {
        float s = bc[t];
#pragma unroll
        for (int c0 = 0; c0 < 32; ++c0) s = fmaf(sg[c0], Wc[c0 * 10 + t], s);
        out[cloud * 10 + t] = s;
    }
}

extern "C" void kernel_launch(void* const* d_in, const int* in_sizes, int n_in,
                              void* d_out, int out_size, void* d_ws, size_t ws_size,
                              hipStream_t stream)
{
    const float* pos = (const float*)d_in[0];
    const float* W1a = (const float*)d_in[2];
    const float* b1a = (const float*)d_in[3];
    const float* W1b = (const float*)d_in[4];
    const float* b1b = (const float*)d_in[5];
    const float* W2a = (const float*)d_in[6];
    const float* b2a = (const float*)d_in[7];
    const float* W2b = (const float*)d_in[8];
    const float* b2b = (const float*)d_in[9];
    const float* Wc  = (const float*)d_in[10];
    const float* bc  = (const float*)d_in[11];

    int*   knn = (int*)d_ws;                                  // 2 MB
    float* h1  = (float*)((char*)d_ws + (size_t)(2 << 20));   // 4 MB
    float* h2  = (float*)((char*)d_ws + (size_t)(6 << 20));   // 4 MB
    float* out = (float*)d_out;

    knn_kernel<<<dim3(NCLOUDS * 32), dim3(512), 0, stream>>>(pos, knn);
    layer_kernel<3><<<dim3((NCLOUDS * N_PER * KNN_K) / 256), dim3(256), 0, stream>>>(
        pos, pos, knn, W1a, b1a, W1b, b1b, h1);
    layer_kernel<32><<<dim3((NCLOUDS * N_PER * KNN_K) / 256), dim3(256), 0, stream>>>(
        pos, h1, knn, W2a, b2a, W2b, b2b, h2);
    pool_kernel<<<dim3(NCLOUDS), dim3(256), 0, stream>>>(h2, Wc, bc, out);
}

// Round 6
// 189.763 us; speedup vs baseline: 3.1799x; 1.0132x over previous
//
#include <hip/hip_runtime.h>
#include <hip/hip_bf16.h>
#include <cstdint>

#define NCLOUDS 16
#define N_PER   2048
#define KNN_K   16
#define CAP     48

typedef unsigned long long u64;

// ---------------------------------------------------------------------------
// KNN v6: grid = 256 blocks (16 clouds x 16 qblocks) = exactly 1 block/CU,
// one round. Block = 512 thr = 8 waves; wave handles 16 queries as 8
// INDEPENDENT PAIRS (ILP-2: two full pipelines interleaved to hide shfl
// latency; v5 ran one serial chain -> VALUBusy 36%). 64 lanes hold 32
// candidates in registers (amdgpu_waves_per_eu(2,2) pins the allocator to
// the 256-VGPR budget; v5's heuristic squeezed to 128 + scratch spill).
// Pass 1 (threshold only): shifted dot-form e = |c|^2 - 2 q.c (4 ops/cand);
// f32 bitonic over 64 lane-minima -> 16th smallest + |q|^2, inflated by
// (1+1e-5)+1e-4 to cover expansion-vs-reference rounding. Upper-bound proof:
// 16 actual d2 values lie at/below the 16th-smallest lane-min. Pass 2: exact
// reference-association d2, collect (d2,idx) u64 for d2<=T into LDS buf.
// Select: 64-lane u64 bitonic -> lanes 0..15 emit exact (d2 asc, idx asc),
// matching jax.lax.top_k tie order.
// ---------------------------------------------------------------------------
__global__ __launch_bounds__(512)
__attribute__((amdgpu_waves_per_eu(2, 2)))
void knn_kernel(const float* __restrict__ pos, int* __restrict__ knn_out)
{
    __shared__ u64 buf[128][CAP];   // 48 KB
    __shared__ int cnt[128];

    const int cloud = blockIdx.x >> 4;
    const int qblk  = blockIdx.x & 15;   // 16 qblocks/cloud, 128 queries each
    const int tid   = threadIdx.x;
    const int wave  = tid >> 6;
    const int lane  = tid & 63;

    if (tid < 128) cnt[tid] = 0;
    __syncthreads();

    const int b0 = cloud * N_PER;

    // candidate registers: slot jj holds point ((2*qblk+jj)&31)*64 + lane
    float cx[32], cy[32], cz[32], sc[32];
#pragma unroll
    for (int jj = 0; jj < 32; ++jj) {
        const int c = (((2 * qblk + jj) & 31) << 6) + lane;
        const float* p = pos + (size_t)(b0 + c) * 3;
        cx[jj] = p[0]; cy[jj] = p[1]; cz[jj] = p[2];
        sc[jj] = fmaf(cz[jj], cz[jj], fmaf(cy[jj], cy[jj], cx[jj] * cx[jj]));
    }

    const int g = wave >> 2;   // which 64-group of the block's 128 queries

#pragma unroll 1
    for (int t = 0; t < 8; ++t) {
        const int qloc0 = wave * 16 + 2 * t;
        const int qloc1 = qloc0 + 1;

        const float sx = g ? cx[1] : cx[0];
        const float sy = g ? cy[1] : cy[0];
        const float sz = g ? cz[1] : cz[0];
        const float Q0x = __shfl(sx, qloc0 & 63), Q1x = __shfl(sx, qloc1 & 63);
        const float Q0y = __shfl(sy, qloc0 & 63), Q1y = __shfl(sy, qloc1 & 63);
        const float Q0z = __shfl(sz, qloc0 & 63), Q1z = __shfl(sz, qloc1 & 63);

        // ---- pass 1 (both queries): min over shifted dot-form distances ----
        const float A0x = -2.0f * Q0x, A0y = -2.0f * Q0y, A0z = -2.0f * Q0z;
        const float A1x = -2.0f * Q1x, A1y = -2.0f * Q1y, A1z = -2.0f * Q1z;
        const float qq0 = fmaf(Q0z, Q0z, fmaf(Q0y, Q0y, Q0x * Q0x));
        const float qq1 = fmaf(Q1z, Q1z, fmaf(Q1y, Q1y, Q1x * Q1x));
        float mn0 = __builtin_inff(), mn1 = __builtin_inff();
#pragma unroll
        for (int jj = 0; jj < 32; ++jj) {
            float e0 = fmaf(cx[jj], A0x, sc[jj]);
            float e1 = fmaf(cx[jj], A1x, sc[jj]);
            e0 = fmaf(cy[jj], A0y, e0);  e1 = fmaf(cy[jj], A1y, e1);
            e0 = fmaf(cz[jj], A0z, e0);  e1 = fmaf(cz[jj], A1z, e1);
            mn0 = fminf(mn0, e0);        mn1 = fminf(mn1, e1);
        }

        // ---- bitonic ascending sort of 64 lane-minima (both, interleaved) ----
        float v0 = mn0, v1 = mn1;
#pragma unroll
        for (int k = 2; k <= 64; k <<= 1) {
#pragma unroll
            for (int j = k >> 1; j >= 1; j >>= 1) {
                const float o0 = __shfl_xor(v0, j);
                const float o1 = __shfl_xor(v1, j);
                const bool keepmin = (((lane & j) == 0) == ((lane & k) == 0));
                v0 = keepmin ? fminf(v0, o0) : fmaxf(v0, o0);
                v1 = keepmin ? fminf(v1, o1) : fmaxf(v1, o1);
            }
        }
        const float T0 = (__shfl(v0, KNN_K - 1) + qq0) * (1.0f + 1e-5f) + 1e-4f;
        const float T1 = (__shfl(v1, KNN_K - 1) + qq1) * (1.0f + 1e-5f) + 1e-4f;

        // ---- pass 2 (both): exact d2 (reference association), collect <= T ----
#pragma unroll
        for (int jj = 0; jj < 32; ++jj) {
            const int c = (((2 * qblk + jj) & 31) << 6) + lane;
            const float dx0 = __fsub_rn(Q0x, cx[jj]);
            const float dy0 = __fsub_rn(Q0y, cy[jj]);
            const float dz0 = __fsub_rn(Q0z, cz[jj]);
            const float d20 = __fadd_rn(__fadd_rn(__fmul_rn(dx0, dx0), __fmul_rn(dy0, dy0)),
                                        __fmul_rn(dz0, dz0));
            if (d20 <= T0) {
                const int slot = atomicAdd(&cnt[qloc0], 1);
                if (slot < CAP)
                    buf[qloc0][slot] = ((u64)__float_as_uint(d20) << 32) | (unsigned)c;
            }
            const float dx1 = __fsub_rn(Q1x, cx[jj]);
            const float dy1 = __fsub_rn(Q1y, cy[jj]);
            const float dz1 = __fsub_rn(Q1z, cz[jj]);
            const float d21 = __fadd_rn(__fadd_rn(__fmul_rn(dx1, dx1), __fmul_rn(dy1, dy1)),
                                        __fmul_rn(dz1, dz1));
            if (d21 <= T1) {
                const int slot = atomicAdd(&cnt[qloc1], 1);
                if (slot < CAP)
                    buf[qloc1][slot] = ((u64)__float_as_uint(d21) << 32) | (unsigned)c;
            }
        }
        asm volatile("s_waitcnt lgkmcnt(0)" ::: "memory");

        // ---- select (both): 64-lane u64 bitonic, lanes 0..15 emit top-16 ----
        const int n0 = min(cnt[qloc0], CAP);
        const int n1 = min(cnt[qloc1], CAP);
        u64 key0 = (lane < n0) ? buf[qloc0][lane] : ~0ULL;
        u64 key1 = (lane < n1) ? buf[qloc1][lane] : ~0ULL;
#pragma unroll
        for (int k = 2; k <= 64; k <<= 1) {
#pragma unroll
            for (int j = k >> 1; j >= 1; j >>= 1) {
                const u64 o0 = __shfl_xor(key0, j);
                const u64 o1 = __shfl_xor(key1, j);
                const bool keepmin = (((lane & j) == 0) == ((lane & k) == 0));
                const u64 lo0 = key0 < o0 ? key0 : o0;
                const u64 hi0 = key0 < o0 ? o0 : key0;
                key0 = keepmin ? lo0 : hi0;
                const u64 lo1 = key1 < o1 ? key1 : o1;
                const u64 hi1 = key1 < o1 ? o1 : key1;
                key1 = keepmin ? lo1 : hi1;
            }
        }
        if (lane < KNN_K) {
            knn_out[((size_t)b0 + qblk * 128 + qloc0) * KNN_K + lane] =
                b0 + (int)(unsigned)(key0 & 0xffffffffu);
            knn_out[((size_t)b0 + qblk * 128 + qloc1) * KNN_K + lane] =
                b0 + (int)(unsigned)(key1 & 0xffffffffu);
        }
    }
}

// ---------------------------------------------------------------------------
// Per-point pre-projection: w[p] = ba + hin[p]@Wa_h + pos[p]@Wa_s,
// v[p] = pos[p]@Wa_s. (x@Wa with x=concat(h_j, p_j-p_i) == w[j] - v[i].)
// Thread = (point, 4-channel group). Reassociation error ~1e-5 << threshold.
// ---------------------------------------------------------------------------
template <int CH>
__global__ __launch_bounds__(256) void pre_kernel(
    const float* __restrict__ pos, const float* __restrict__ hin,
    const float* __restrict__ Wa, const float* __restrict__ ba,
    float* __restrict__ w, float* __restrict__ v)
{
    const int gth = blockIdx.x * 256 + threadIdx.x;
    const int p   = gth >> 3;
    const int i8  = gth & 7;
    const float4* Wa4 = (const float4*)Wa;
    const float4* ba4 = (const float4*)ba;

    float4 acc = ba4[i8];
    const float* hrow = hin + (size_t)p * CH;
#pragma unroll
    for (int d = 0; d < CH; ++d) {
        const float h = hrow[d];
        const float4 wr = Wa4[d * 8 + i8];
        acc.x = fmaf(h, wr.x, acc.x);
        acc.y = fmaf(h, wr.y, acc.y);
        acc.z = fmaf(h, wr.z, acc.z);
        acc.w = fmaf(h, wr.w, acc.w);
    }
    float4 vs = make_float4(0.f, 0.f, 0.f, 0.f);
    const float* prow = pos + (size_t)p * 3;
#pragma unroll
    for (int d = 0; d < 3; ++d) {
        const float pd = prow[d];
        const float4 wr = Wa4[(CH + d) * 8 + i8];
        vs.x = fmaf(pd, wr.x, vs.x);
        vs.y = fmaf(pd, wr.y, vs.y);
        vs.z = fmaf(pd, wr.z, vs.z);
        vs.w = fmaf(pd, wr.w, vs.w);
    }
    ((float4*)w)[(size_t)p * 8 + i8] =
        make_float4(acc.x + vs.x, acc.y + vs.y, acc.z + vs.z, acc.w + vs.w);
    ((float4*)v)[(size_t)p * 8 + i8] = vs;
}

// ---------------------------------------------------------------------------
// Edge-MLP layer (both layers): lane = one edge (p,k). First MLP collapses to
// hid = relu(w[j] - v[p]) via pre-projection. Second GEMM per edge (32x32
// fma), max over the 16 edge-lanes via shfl_xor butterfly, outer relu.
// ---------------------------------------------------------------------------
__global__ __launch_bounds__(256) void layer_kernel(
    const int*   __restrict__ knn,
    const float* __restrict__ Wb, const float* __restrict__ bb,
    const float* __restrict__ w,  const float* __restrict__ v,
    float* __restrict__ hout)
{
    const int gth = blockIdx.x * 256 + threadIdx.x;
    const int p = gth >> 4;
    const int k = gth & 15;
    const int j = knn[gth];

    const float4* w4 = (const float4*)w;
    const float4* v4 = (const float4*)v;

    float hid[32];
#pragma unroll
    for (int i = 0; i < 8; ++i) {
        const float4 a = w4[(size_t)j * 8 + i];
        const float4 b = v4[(size_t)p * 8 + i];
        hid[4 * i + 0] = fmaxf(a.x - b.x, 0.0f);
        hid[4 * i + 1] = fmaxf(a.y - b.y, 0.0f);
        hid[4 * i + 2] = fmaxf(a.z - b.z, 0.0f);
        hid[4 * i + 3] = fmaxf(a.w - b.w, 0.0f);
    }

    float o0 = 0.0f, o1 = 0.0f;
#pragma unroll
    for (int c2 = 0; c2 < 32; ++c2) {
        float s = bb[c2];
#pragma unroll
        for (int c = 0; c < 32; ++c) s = fmaf(hid[c], Wb[c * 32 + c2], s);
        s = fmaxf(s, __shfl_xor(s, 1));
        s = fmaxf(s, __shfl_xor(s, 2));
        s = fmaxf(s, __shfl_xor(s, 4));
        s = fmaxf(s, __shfl_xor(s, 8));
        if ((c2 & 15) == k) { if (c2 < 16) o0 = s; else o1 = s; }
    }
    hout[(size_t)p * 32 + k]      = fmaxf(o0, 0.0f);
    hout[(size_t)p * 32 + 16 + k] = fmaxf(o1, 0.0f);
}

// ---------------------------------------------------------------------------
// Global max pool over each cloud + linear classifier. 1 block per cloud.
// ---------------------------------------------------------------------------
__global__ __launch_bounds__(256) void pool_kernel(
    const float* __restrict__ h2, const float* __restrict__ Wc,
    const float* __restrict__ bc, float* __restrict__ out)
{
    __shared__ float red[8][32];
    __shared__ float sg[32];
    const int cloud = blockIdx.x;
    const int t = threadIdx.x;
    const int c = t & 31, row = t >> 5;
    float m = 0.0f;  // h2 >= 0 after relu
    for (int p = row; p < N_PER; p += 8)
        m = fmaxf(m, h2[((size_t)cloud * N_PER + p) * 32 + c]);
    red[row][c] = m;
    __syncthreads();
    if (t < 32) {
        float gv = red[0][t];
#pragma unroll
        for (int r = 1; r < 8; ++r) gv = fmaxf(gv, red[r][t]);
        sg[t] = gv;
    }
    __syncthreads();
    if (t < 10) {
        float s = bc[t];
#pragma unroll
        for (int c0 = 0; c0 < 32; ++c0) s = fmaf(sg[c0], Wc[c0 * 10 + t], s);
        out[cloud * 10 + t] = s;
    }
}

extern "C" void kernel_launch(void* const* d_in, const int* in_sizes, int n_in,
                              void* d_out, int out_size, void* d_ws, size_t ws_size,
                              hipStream_t stream)
{
    const float* pos = (const float*)d_in[0];
    const float* W1a = (const float*)d_in[2];
    const float* b1a = (const float*)d_in[3];
    const float* W1b = (const float*)d_in[4];
    const float* b1b = (const float*)d_in[5];
    const float* W2a = (const float*)d_in[6];
    const float* b2a = (const float*)d_in[7];
    const float* W2b = (const float*)d_in[8];
    const float* b2b = (const float*)d_in[9];
    const float* Wc  = (const float*)d_in[10];
    const float* bc  = (const float*)d_in[11];

    int*   knn = (int*)d_ws;                                   // 2 MB
    float* w   = (float*)((char*)d_ws + (size_t)(2  << 20));   // 4 MB
    float* v   = (float*)((char*)d_ws + (size_t)(6  << 20));   // 4 MB
    float* h1  = (float*)((char*)d_ws + (size_t)(10 << 20));   // 4 MB
    float* h2  = h1;   // h1 dead after pre2; layer2 reads only w,v
    float* out = (float*)d_out;

    const int npts = NCLOUDS * N_PER;

    knn_kernel<<<dim3(NCLOUDS * 16), dim3(512), 0, stream>>>(pos, knn);
    pre_kernel<3><<<dim3(npts * 8 / 256), dim3(256), 0, stream>>>(
        pos, pos, W1a, b1a, w, v);
    layer_kernel<<<dim3(npts * KNN_K / 256), dim3(256), 0, stream>>>(
        knn, W1b, b1b, w, v, h1);
    pre_kernel<32><<<dim3(npts * 8 / 256), dim3(256), 0, stream>>>(
        pos, h1, W2a, b2a, w, v);
    layer_kernel<<<dim3(npts * KNN_K / 256), dim3(256), 0, stream>>>(
        knn, W2b, b2b, w, v, h2);
    pool_kernel<<<dim3(NCLOUDS), dim3(256), 0, stream>>>(h2, Wc, bc, out);
}